// Round 7
// baseline (1164.579 us; speedup 1.0000x reference)
//
#include <hip/hip_runtime.h>

#define N_NODES 20000
#define N_EDGES 320000
#define EDG_ALL (N_EDGES + N_NODES)
#define F_IN 128
#define HID 512
#define NB 64
#define NCLS 38
#define M_PAD 20096        // 157 * 128
#define NBLK_SCAN ((N_NODES + 255) / 256)   // 79

typedef short bf16x8 __attribute__((ext_vector_type(8)));
typedef float f32x4 __attribute__((ext_vector_type(4)));
typedef _Float16 f16;
typedef _Float16 f16x2 __attribute__((ext_vector_type(2)));

__device__ inline unsigned short f2bf(float f) {
  union { float f; unsigned u; } v; v.f = f;
  unsigned r = v.u + 0x7FFF + ((v.u >> 16) & 1);
  return (unsigned short)(r >> 16);
}

// split f into hi(bf16) + lo(bf16 of residual)
__device__ inline void split2(float f, unsigned short& h, unsigned short& l) {
  unsigned short hh = f2bf(f);
  union { unsigned u; float f; } vh; vh.u = ((unsigned)hh) << 16;
  h = hh;
  l = f2bf(f - vh.f);
}

__device__ inline void gload16(const void* g, void* l) {
  __builtin_amdgcn_global_load_lds(
      (const __attribute__((address_space(1))) unsigned int*)g,
      (__attribute__((address_space(3))) unsigned int*)l, 16, 0, 0);
}

// ---------------- graph preprocessing ----------------

__global__ void deg_count(const int* __restrict__ ei, int* __restrict__ deg) {
  int e = blockIdx.x * blockDim.x + threadIdx.x;
  if (e >= EDG_ALL) return;
  int d = (e < N_EDGES) ? ei[N_EDGES + e] : (e - N_EDGES);
  atomicAdd(&deg[d], 1);
}

__global__ void scan_p1(const int* __restrict__ deg, int* __restrict__ bsum) {
  __shared__ int sh[256];
  int b = blockIdx.x, t = threadIdx.x, i = b * 256 + t;
  sh[t] = (i < N_NODES) ? deg[i] : 0;
  __syncthreads();
  for (int o = 128; o > 0; o >>= 1) {
    if (t < o) sh[t] += sh[t + o];
    __syncthreads();
  }
  if (t == 0) bsum[b] = sh[0];
}

__global__ void scan_p2(const int* __restrict__ bsum, int* __restrict__ boff) {
  __shared__ int sh[128];
  int t = threadIdx.x;
  sh[t] = (t < NBLK_SCAN) ? bsum[t] : 0;
  __syncthreads();
  for (int o = 1; o < 128; o <<= 1) {
    int v = (t >= o) ? sh[t - o] : 0;
    __syncthreads();
    sh[t] += v;
    __syncthreads();
  }
  boff[t] = (t == 0) ? 0 : sh[t - 1];
}

__global__ void scan_p3(const int* __restrict__ deg, const int* __restrict__ boff,
                        int* __restrict__ row_ptr) {
  __shared__ int sh[256];
  int b = blockIdx.x, t = threadIdx.x, i = b * 256 + t;
  sh[t] = (i < N_NODES) ? deg[i] : 0;
  __syncthreads();
  for (int o = 1; o < 256; o <<= 1) {
    int v = (t >= o) ? sh[t - o] : 0;
    __syncthreads();
    sh[t] += v;
    __syncthreads();
  }
  if (i < N_NODES) row_ptr[i + 1] = boff[b] + sh[t];
  if (i == 0) row_ptr[0] = 0;
}

__global__ void compute_norm(const int* __restrict__ deg, float* __restrict__ norm) {
  int i = blockIdx.x * blockDim.x + threadIdx.x;
  if (i >= N_NODES) return;
  norm[i] = rsqrtf(fmaxf((float)deg[i], 1.f));
}

__global__ void fill_csr(const int* __restrict__ ei, int* __restrict__ cursor,
                         int* __restrict__ csr_src) {
  int e = blockIdx.x * blockDim.x + threadIdx.x;
  if (e >= EDG_ALL) return;
  int s, d;
  if (e < N_EDGES) { s = ei[e]; d = ei[N_EDGES + e]; }
  else { s = d = e - N_EDGES; }
  int pos = atomicAdd(&cursor[d], 1);
  csr_src[pos] = s;
}

// ---------------- conversions / transposes ----------------

__global__ void conv_split4(const float* __restrict__ in, unsigned short* __restrict__ hi,
                            unsigned short* __restrict__ lo, int n4) {
  int i = blockIdx.x * blockDim.x + threadIdx.x;
  if (i >= n4) return;
  float4 v = ((const float4*)in)[i];
  ushort4 h, l;
  split2(v.x, h.x, l.x); split2(v.y, h.y, l.y);
  split2(v.z, h.z, l.z); split2(v.w, h.w, l.w);
  ((ushort4*)hi)[i] = h;
  ((ushort4*)lo)[i] = l;
}

// W [K][N] fp32 -> WT hi/lo [N][K] bf16   (K, N multiples of 32)
__global__ __launch_bounds__(256) void wtrans_split(const float* __restrict__ W,
                                                    unsigned short* __restrict__ WTh,
                                                    unsigned short* __restrict__ WTl,
                                                    int K, int N) {
  __shared__ float sh[32][33];
  int k0 = blockIdx.y * 32, n0 = blockIdx.x * 32;
  int r = threadIdx.x >> 5, c = threadIdx.x & 31;
#pragma unroll
  for (int i = 0; i < 4; ++i)
    sh[r + 8 * i][c] = W[(size_t)(k0 + r + 8 * i) * N + n0 + c];
  __syncthreads();
#pragma unroll
  for (int i = 0; i < 4; ++i) {
    unsigned short h, l;
    split2(sh[c][r + 8 * i], h, l);
    WTh[(size_t)(n0 + r + 8 * i) * K + k0 + c] = h;
    WTl[(size_t)(n0 + r + 8 * i) * K + k0 + c] = l;
  }
}

// W [K][N] fp32 -> WT [N][K] fp32, bounds-checked
__global__ __launch_bounds__(256) void ftrans(const float* __restrict__ W,
                                              float* __restrict__ WT, int K, int N) {
  __shared__ float sh[32][33];
  int k0 = blockIdx.y * 32, n0 = blockIdx.x * 32;
  int r = threadIdx.x >> 5, c = threadIdx.x & 31;
#pragma unroll
  for (int i = 0; i < 4; ++i) {
    int k = k0 + r + 8 * i, n = n0 + c;
    sh[r + 8 * i][c] = (k < K && n < N) ? W[(size_t)k * N + n] : 0.f;
  }
  __syncthreads();
#pragma unroll
  for (int i = 0; i < 4; ++i) {
    int n = n0 + r + 8 * i, k = k0 + c;
    if (n < N && k < K) WT[(size_t)n * K + k] = sh[c][r + 8 * i];
  }
}

// ---------------- split-bf16 MFMA GEMM ----------------
// C[M_PAD][512] = (Ah+Al)[M_PAD][K] * (Bh+Bl)[512][K]^T, dropping Al*Bl

template <int K, typename OT>
__global__ __launch_bounds__(256) void mm_split(const unsigned short* __restrict__ Ah,
                                                const unsigned short* __restrict__ Al,
                                                const unsigned short* __restrict__ Bh,
                                                const unsigned short* __restrict__ Bl,
                                                const float* __restrict__ bias,
                                                OT* __restrict__ C) {
  __shared__ unsigned short AsH[4096], AsL[4096], BsH[4096], BsL[4096];
  const int t = threadIdx.x;
  const int wid = t >> 6, l = t & 63;
  const int row0 = blockIdx.y * 128;
  const int col0 = blockIdx.x * 128;
  const int wm = wid >> 1, wn = wid & 1;

  f32x4 acc[4][4];
#pragma unroll
  for (int m = 0; m < 4; ++m)
#pragma unroll
    for (int n = 0; n < 4; ++n)
#pragma unroll
      for (int q = 0; q < 4; ++q) acc[m][n][q] = 0.f;

  const size_t aoff = (size_t)(row0 + wid * 32 + (l >> 2)) * K + (l & 3) * 8;
  const size_t boff = (size_t)(col0 + wid * 32 + (l >> 2)) * K + (l & 3) * 8;
  const unsigned short* gAh0 = Ah + aoff; const unsigned short* gAh1 = gAh0 + (size_t)16 * K;
  const unsigned short* gAl0 = Al + aoff; const unsigned short* gAl1 = gAl0 + (size_t)16 * K;
  const unsigned short* gBh0 = Bh + boff; const unsigned short* gBh1 = gBh0 + (size_t)16 * K;
  const unsigned short* gBl0 = Bl + boff; const unsigned short* gBl1 = gBl0 + (size_t)16 * K;
  unsigned short* lAh0 = &AsH[(wid * 2 + 0) * 512];
  unsigned short* lAh1 = &AsH[(wid * 2 + 1) * 512];
  unsigned short* lAl0 = &AsL[(wid * 2 + 0) * 512];
  unsigned short* lAl1 = &AsL[(wid * 2 + 1) * 512];
  unsigned short* lBh0 = &BsH[(wid * 2 + 0) * 512];
  unsigned short* lBh1 = &BsH[(wid * 2 + 1) * 512];
  unsigned short* lBl0 = &BsL[(wid * 2 + 0) * 512];
  unsigned short* lBl1 = &BsL[(wid * 2 + 1) * 512];

  const int lr = l & 15, kq = (l >> 4) * 8;

  for (int kt = 0; kt < K / 32; ++kt) {
    const int ko = kt * 32;
    gload16(gAh0 + ko, lAh0);
    gload16(gAh1 + ko, lAh1);
    gload16(gAl0 + ko, lAl0);
    gload16(gAl1 + ko, lAl1);
    gload16(gBh0 + ko, lBh0);
    gload16(gBh1 + ko, lBh1);
    gload16(gBl0 + ko, lBl0);
    gload16(gBl1 + ko, lBl1);
    __syncthreads();
    bf16x8 ah[4], al[4], bh[4], bl[4];
#pragma unroll
    for (int m = 0; m < 4; ++m) {
      int ro = (wm * 64 + m * 16 + lr) * 32 + kq;
      ah[m] = *(const bf16x8*)&AsH[ro];
      al[m] = *(const bf16x8*)&AsL[ro];
    }
#pragma unroll
    for (int n = 0; n < 4; ++n) {
      int ro = (wn * 64 + n * 16 + lr) * 32 + kq;
      bh[n] = *(const bf16x8*)&BsH[ro];
      bl[n] = *(const bf16x8*)&BsL[ro];
    }
#pragma unroll
    for (int m = 0; m < 4; ++m)
#pragma unroll
      for (int n = 0; n < 4; ++n) {
        acc[m][n] = __builtin_amdgcn_mfma_f32_16x16x32_bf16(ah[m], bh[n], acc[m][n], 0, 0, 0);
        acc[m][n] = __builtin_amdgcn_mfma_f32_16x16x32_bf16(al[m], bh[n], acc[m][n], 0, 0, 0);
        acc[m][n] = __builtin_amdgcn_mfma_f32_16x16x32_bf16(ah[m], bl[n], acc[m][n], 0, 0, 0);
      }
    __syncthreads();
  }

  const int lg = l >> 4;
#pragma unroll
  for (int m = 0; m < 4; ++m) {
    int row = row0 + wm * 64 + m * 16 + lg * 4;
#pragma unroll
    for (int n = 0; n < 4; ++n) {
      int col = col0 + wn * 64 + n * 16 + lr;
      float bv = bias ? bias[col] : 0.f;
#pragma unroll
      for (int j = 0; j < 4; ++j)
        C[(size_t)(row + j) * HID + col] = (OT)(acc[m][n][j] + bv);
    }
  }
}

// ---------------- batchnorm (train-mode, over rows) ----------------

__global__ __launch_bounds__(256) void colstats(const float* __restrict__ X, int n,
                                                float* __restrict__ stats) {
  int t = threadIdx.x;
  int r0 = blockIdx.x * 128;
  int r1 = min(r0 + 128, n);
  float s0 = 0, q0 = 0, s1 = 0, q1 = 0;
  for (int r = r0; r < r1; ++r) {
    float a = X[(size_t)r * HID + t];
    float b = X[(size_t)r * HID + t + 256];
    s0 += a; q0 += a * a;
    s1 += b; q1 += b * b;
  }
  atomicAdd(&stats[t], s0);
  atomicAdd(&stats[t + 256], s1);
  atomicAdd(&stats[HID + t], q0);
  atomicAdd(&stats[HID + t + 256], q1);
}

// act: 1=leaky_relu(0.2), 2=elu ; writes bf16 hi/lo planes; fp32 X in place only if writeX
__global__ __launch_bounds__(256) void bn_act(float* __restrict__ X, int n,
                                              const float* __restrict__ stats,
                                              const float* __restrict__ g,
                                              const float* __restrict__ b, int act,
                                              unsigned short* __restrict__ hio,
                                              unsigned short* __restrict__ loo,
                                              int writeX) {
  int t = threadIdx.x;
  int r0 = blockIdx.x * 128;
  int r1 = min(r0 + 128, n);
  float invn = 1.f / (float)n;
  float mu0 = stats[t] * invn, mu1 = stats[t + 256] * invn;
  float v0 = stats[HID + t] * invn - mu0 * mu0;
  float v1 = stats[HID + t + 256] * invn - mu1 * mu1;
  float sc0 = g[t] * rsqrtf(v0 + 1e-5f);
  float sc1 = g[t + 256] * rsqrtf(v1 + 1e-5f);
  float b0 = b[t], b1 = b[t + 256];
  for (int r = r0; r < r1; ++r) {
    float y0 = sc0 * (X[(size_t)r * HID + t] - mu0) + b0;
    float y1 = sc1 * (X[(size_t)r * HID + t + 256] - mu1) + b1;
    if (act == 1) {
      y0 = y0 > 0.f ? y0 : 0.2f * y0;
      y1 = y1 > 0.f ? y1 : 0.2f * y1;
    } else {
      y0 = y0 > 0.f ? y0 : expm1f(y0);
      y1 = y1 > 0.f ? y1 : expm1f(y1);
    }
    unsigned short h0, l0, h1, l1;
    split2(y0, h0, l0);
    split2(y1, h1, l1);
    hio[(size_t)r * HID + t] = h0;
    hio[(size_t)r * HID + t + 256] = h1;
    loo[(size_t)r * HID + t] = l0;
    loo[(size_t)r * HID + t + 256] = l1;
    if (writeX) {
      X[(size_t)r * HID + t] = y0;
      X[(size_t)r * HID + t + 256] = y1;
    }
  }
}

// ---------------- GCN aggregation (fp16 features, unrolled x4) ----------------

__global__ __launch_bounds__(256) void gcn_agg_h(
    const f16* __restrict__ h, const int* __restrict__ row_ptr,
    const int* __restrict__ csr_src, const float* __restrict__ norm,
    const float* __restrict__ bias, float* __restrict__ out) {
  int i = blockIdx.x;
  int t = threadIdx.x;
  int beg = row_ptr[i], end = row_ptr[i + 1];
  float ni = norm[i];
  const f16x2* h2 = (const f16x2*)h;
  float a0 = 0.f, a1 = 0.f;
  int e = beg;
  for (; e + 4 <= end; e += 4) {
    int s0 = csr_src[e], s1 = csr_src[e + 1], s2 = csr_src[e + 2], s3 = csr_src[e + 3];
    float c0 = norm[s0] * ni, c1 = norm[s1] * ni, c2 = norm[s2] * ni, c3 = norm[s3] * ni;
    f16x2 v0 = h2[(size_t)s0 * 256 + t];
    f16x2 v1 = h2[(size_t)s1 * 256 + t];
    f16x2 v2 = h2[(size_t)s2 * 256 + t];
    f16x2 v3 = h2[(size_t)s3 * 256 + t];
    a0 += c0 * (float)v0.x + c1 * (float)v1.x + c2 * (float)v2.x + c3 * (float)v3.x;
    a1 += c0 * (float)v0.y + c1 * (float)v1.y + c2 * (float)v2.y + c3 * (float)v3.y;
  }
  for (; e < end; ++e) {
    int s = csr_src[e];
    float c = norm[s] * ni;
    f16x2 hv = h2[(size_t)s * 256 + t];
    a0 += c * (float)hv.x;
    a1 += c * (float)hv.y;
  }
  float2 bv = ((const float2*)bias)[t];
  float2 o; o.x = a0 + bv.x; o.y = a1 + bv.y;
  ((float2*)out)[(size_t)i * 256 + t] = o;
}

// ---------------- GAT ----------------

__device__ inline float wave_sum(float v) {
#pragma unroll
  for (int o = 32; o > 0; o >>= 1) v += __shfl_down(v, o);
  return v;
}
__device__ inline float wave_max(float v) {
#pragma unroll
  for (int o = 32; o > 0; o >>= 1) v = fmaxf(v, __shfl_down(v, o));
  return v;
}

// asn/adn from fp16 h: thread t covers features 2t,2t+1 (head = t>=128)
__global__ __launch_bounds__(256) void gat_prep_h(
    const f16* __restrict__ h, const float* __restrict__ a_src,
    const float* __restrict__ a_dst, float* __restrict__ asn, float* __restrict__ adn) {
  int i = blockIdx.x;
  int t = threadIdx.x;
  f16x2 hv = ((const f16x2*)h)[(size_t)i * 256 + t];
  float2 as2 = ((const float2*)a_src)[t];
  float2 ad2 = ((const float2*)a_dst)[t];
  float h0 = (float)hv.x, h1 = (float)hv.y;
  float s = h0 * as2.x + h1 * as2.y;
  float d = h0 * ad2.x + h1 * ad2.y;
  s = wave_sum(s); d = wave_sum(d);
  __shared__ float red[4][2];
  int w = t >> 6;
  if ((t & 63) == 0) { red[w][0] = s; red[w][1] = d; }
  __syncthreads();
  if (t == 0) {
    asn[2 * i]     = red[0][0] + red[1][0];   // head 0 = waves 0,1 (threads 0-127)
    asn[2 * i + 1] = red[2][0] + red[3][0];   // head 1 = waves 2,3
    adn[2 * i]     = red[0][1] + red[1][1];
    adn[2 * i + 1] = red[2][1] + red[3][1];
  }
}

// 3-pass: per-node max, sumexp, weighted fp16 gather (pass 3 unrolled x4)
__global__ __launch_bounds__(256) void gat_agg_h(
    const f16* __restrict__ h, const int* __restrict__ row_ptr,
    const int* __restrict__ csr_src, const float* __restrict__ asn,
    const float* __restrict__ adn, const float* __restrict__ bias,
    float* __restrict__ out) {
  int i = blockIdx.x;
  int t = threadIdx.x;
  int beg = row_ptr[i], end = row_ptr[i + 1];
  float ad0 = adn[2 * i], ad1 = adn[2 * i + 1];

  // pass 1: max of leaky_relu(as[src]+ad[dst]) per head
  float m0 = -3.4e38f, m1 = -3.4e38f;
  for (int e = beg + t; e < end; e += 256) {
    int s = csr_src[e];
    float e0 = asn[2 * s] + ad0;     e0 = e0 > 0.f ? e0 : 0.2f * e0;
    float e1 = asn[2 * s + 1] + ad1; e1 = e1 > 0.f ? e1 : 0.2f * e1;
    m0 = fmaxf(m0, e0); m1 = fmaxf(m1, e1);
  }
  __shared__ float red0[4], red1[4];
  float r0 = wave_max(m0), r1 = wave_max(m1);
  if ((t & 63) == 0) { red0[t >> 6] = r0; red1[t >> 6] = r1; }
  __syncthreads();
  float M0 = fmaxf(fmaxf(red0[0], red0[1]), fmaxf(red0[2], red0[3]));
  float M1 = fmaxf(fmaxf(red1[0], red1[1]), fmaxf(red1[2], red1[3]));
  __syncthreads();

  // pass 2: sum of exp(e - M)
  float t0 = 0.f, t1 = 0.f;
  for (int e = beg + t; e < end; e += 256) {
    int s = csr_src[e];
    float e0 = asn[2 * s] + ad0;     e0 = e0 > 0.f ? e0 : 0.2f * e0;
    float e1 = asn[2 * s + 1] + ad1; e1 = e1 > 0.f ? e1 : 0.2f * e1;
    t0 += expf(e0 - M0); t1 += expf(e1 - M1);
  }
  r0 = wave_sum(t0); r1 = wave_sum(t1);
  if ((t & 63) == 0) { red0[t >> 6] = r0; red1[t >> 6] = r1; }
  __syncthreads();
  float iS0 = 1.f / (red0[0] + red0[1] + red0[2] + red0[3]);
  float iS1 = 1.f / (red1[0] + red1[1] + red1[2] + red1[3]);
  __syncthreads();

  // pass 3: weighted feature gather, chunks of 64 edges, unrolled x4
  __shared__ float w0s[64], w1s[64];
  __shared__ int ss[64];
  const f16x2* h2 = (const f16x2*)h;
  float acc0 = 0.f, acc1 = 0.f;
  for (int c = beg; c < end; c += 64) {
    int nc = min(64, end - c);
    if (t < nc) {
      int s = csr_src[c + t];
      ss[t] = s;
      float e0 = asn[2 * s] + ad0;     e0 = e0 > 0.f ? e0 : 0.2f * e0;
      float e1 = asn[2 * s + 1] + ad1; e1 = e1 > 0.f ? e1 : 0.2f * e1;
      w0s[t] = expf(e0 - M0) * iS0;
      w1s[t] = expf(e1 - M1) * iS1;
    }
    __syncthreads();
    int j = 0;
    for (; j + 4 <= nc; j += 4) {
      int s0 = ss[j], s1 = ss[j + 1], s2 = ss[j + 2], s3 = ss[j + 3];
      f16x2 v0 = h2[(size_t)s0 * 256 + t];
      f16x2 v1 = h2[(size_t)s1 * 256 + t];
      f16x2 v2 = h2[(size_t)s2 * 256 + t];
      f16x2 v3 = h2[(size_t)s3 * 256 + t];
      float u0 = (t < 128) ? w0s[j]     : w1s[j];
      float u1 = (t < 128) ? w0s[j + 1] : w1s[j + 1];
      float u2 = (t < 128) ? w0s[j + 2] : w1s[j + 2];
      float u3 = (t < 128) ? w0s[j + 3] : w1s[j + 3];
      acc0 += u0 * (float)v0.x + u1 * (float)v1.x + u2 * (float)v2.x + u3 * (float)v3.x;
      acc1 += u0 * (float)v0.y + u1 * (float)v1.y + u2 * (float)v2.y + u3 * (float)v3.y;
    }
    for (; j < nc; ++j) {
      int s = ss[j];
      f16x2 hv = h2[(size_t)s * 256 + t];
      float w = (t < 128) ? w0s[j] : w1s[j];
      acc0 += w * (float)hv.x;
      acc1 += w * (float)hv.y;
    }
    __syncthreads();
  }
  float2 bv = ((const float2*)bias)[t];
  float2 o; o.x = acc0 + bv.x; o.y = acc1 + bv.y;
  ((float2*)out)[(size_t)i * 256 + t] = o;
}

// ---------------- pooling ----------------

__global__ void graph_starts(const int* __restrict__ batch, int* __restrict__ start) {
  int i = blockIdx.x * blockDim.x + threadIdx.x;
  if (i >= N_NODES) return;
  int b = batch[i];
  int bp = (i == 0) ? -1 : batch[i - 1];
  for (int g = bp + 1; g <= b; ++g) start[g] = i;
  if (i == N_NODES - 1) {
    for (int g = b + 1; g <= NB; ++g) start[g] = N_NODES;
  }
}

__global__ __launch_bounds__(512) void pool2(const float* __restrict__ h,
                                             const int* __restrict__ start,
                                             float* __restrict__ p) {
  int b = blockIdx.x, t = threadIdx.x;
  int s = start[b], e = start[b + 1];
  float sum = 0.f, mx = -3.4e38f;
  int r = s;
  for (; r + 4 <= e; r += 4) {
    float v0 = h[(size_t)(r + 0) * HID + t];
    float v1 = h[(size_t)(r + 1) * HID + t];
    float v2 = h[(size_t)(r + 2) * HID + t];
    float v3 = h[(size_t)(r + 3) * HID + t];
    sum += v0 + v1 + v2 + v3;
    mx = fmaxf(mx, fmaxf(fmaxf(v0, v1), fmaxf(v2, v3)));
  }
  for (; r < e; ++r) {
    float v = h[(size_t)r * HID + t];
    sum += v; mx = fmaxf(mx, v);
  }
  float cnt = (float)(e - s);
  p[b * 1024 + t] = sum / fmaxf(cnt, 1.f);
  p[b * 1024 + 512 + t] = mx;
}

// ---------------- classifier ----------------

__global__ __launch_bounds__(256) void fc_wave(const float* __restrict__ A,
                                               const float* __restrict__ WT,
                                               const float* __restrict__ bias,
                                               float* __restrict__ C, int K, int Ncol) {
  int r = blockIdx.x;
  int wid = threadIdx.x >> 6, l = threadIdx.x & 63;
  int c = blockIdx.y * 4 + wid;
  if (c >= Ncol) return;
  const float* a = A + (size_t)r * K;
  const float* w = WT + (size_t)c * K;
  float s = 0.f;
  for (int k = l; k < K; k += 64) s += a[k] * w[k];
#pragma unroll
  for (int o = 32; o > 0; o >>= 1) s += __shfl_down(s, o);
  if (l == 0) C[(size_t)r * Ncol + c] = s + bias[c];
}

__global__ void bn_small(float* __restrict__ X, int R, int C,
                         const float* __restrict__ g, const float* __restrict__ b, int act) {
  int c = blockIdx.x * blockDim.x + threadIdx.x;
  if (c >= C) return;
  float s = 0.f, q = 0.f;
  for (int r = 0; r < R; ++r) {
    float v = X[r * C + c];
    s += v; q += v * v;
  }
  float mu = s / R;
  float var = q / R - mu * mu;
  float sc = g[c] * rsqrtf(var + 1e-5f);
  float bb = b[c];
  for (int r = 0; r < R; ++r) {
    float v = sc * (X[r * C + c] - mu) + bb;
    if (act == 1) v = v > 0.f ? v : 0.2f * v;
    X[r * C + c] = v;
  }
}

// ---------------- launch ----------------

extern "C" void kernel_launch(void* const* d_in, const int* in_sizes, int n_in,
                              void* d_out, int out_size, void* d_ws, size_t ws_size,
                              hipStream_t stream) {
  const float* x      = (const float*)d_in[0];
  const int*   ei     = (const int*)d_in[1];
  const int*   batch  = (const int*)d_in[2];
  const float* ft_W   = (const float*)d_in[3];
  const float* ft_b   = (const float*)d_in[4];
  const float* ft_g   = (const float*)d_in[5];
  const float* ft_be  = (const float*)d_in[6];
  const float* gcn1_W = (const float*)d_in[7];
  const float* gcn1_b = (const float*)d_in[8];
  const float* gbn1_g = (const float*)d_in[9];
  const float* gbn1_b = (const float*)d_in[10];
  const float* gcn2_W = (const float*)d_in[11];
  const float* gcn2_b = (const float*)d_in[12];
  const float* gbn2_g = (const float*)d_in[13];
  const float* gbn2_b = (const float*)d_in[14];
  const float* gat1_W = (const float*)d_in[15];
  const float* gat1_as= (const float*)d_in[16];
  const float* gat1_ad= (const float*)d_in[17];
  const float* gat1_b = (const float*)d_in[18];
  const float* abn1_g = (const float*)d_in[19];
  const float* abn1_b = (const float*)d_in[20];
  const float* gat2_W = (const float*)d_in[21];
  const float* gat2_as= (const float*)d_in[22];
  const float* gat2_ad= (const float*)d_in[23];
  const float* gat2_b = (const float*)d_in[24];
  const float* abn2_g = (const float*)d_in[25];
  const float* abn2_b = (const float*)d_in[26];
  const float* fc1_W  = (const float*)d_in[27];
  const float* fc1_b  = (const float*)d_in[28];
  const float* cbn1_g = (const float*)d_in[29];
  const float* cbn1_b = (const float*)d_in[30];
  const float* fc2_W  = (const float*)d_in[31];
  const float* fc2_b  = (const float*)d_in[32];
  const float* cbn2_g = (const float*)d_in[33];
  const float* cbn2_b = (const float*)d_in[34];
  const float* out_W  = (const float*)d_in[35];
  const float* out_b  = (const float*)d_in[36];

  char* ws = (char*)d_ws;
  size_t off = 0;
  auto alloc = [&](size_t bytes) -> void* {
    void* p = ws + off;
    off = (off + bytes + 255) & ~(size_t)255;
    return p;
  };

  float* buf0 = (float*)alloc((size_t)N_NODES * HID * 4);      // fp32 agg out (aliases xhi/xlo early)
  float* buf1 = (float*)alloc((size_t)M_PAD * HID * 4);        // GEMM out (fp32 for ft; fp16 view for layers)
  unsigned short* ahi = (unsigned short*)alloc((size_t)N_NODES * HID * 2);
  unsigned short* alo = (unsigned short*)alloc((size_t)N_NODES * HID * 2);
  unsigned short* wh_ft = (unsigned short*)alloc((size_t)HID * F_IN * 2);
  unsigned short* wl_ft = (unsigned short*)alloc((size_t)HID * F_IN * 2);
  unsigned short* wh_g1 = (unsigned short*)alloc((size_t)HID * HID * 2);
  unsigned short* wl_g1 = (unsigned short*)alloc((size_t)HID * HID * 2);
  unsigned short* wh_g2 = (unsigned short*)alloc((size_t)HID * HID * 2);
  unsigned short* wl_g2 = (unsigned short*)alloc((size_t)HID * HID * 2);
  unsigned short* wh_a1 = (unsigned short*)alloc((size_t)HID * HID * 2);
  unsigned short* wl_a1 = (unsigned short*)alloc((size_t)HID * HID * 2);
  unsigned short* wh_a2 = (unsigned short*)alloc((size_t)HID * HID * 2);
  unsigned short* wl_a2 = (unsigned short*)alloc((size_t)HID * HID * 2);
  float* fc1t = (float*)alloc((size_t)512 * 1024 * 4);
  float* fc2t = (float*)alloc((size_t)256 * 512 * 4);
  float* outt = (float*)alloc((size_t)NCLS * 256 * 4);
  int*   row_ptr = (int*)alloc((N_NODES + 1) * 4);
  int*   cursor  = (int*)alloc(N_NODES * 4);
  int*   deg     = (int*)alloc(N_NODES * 4);
  int*   csr_src = (int*)alloc(EDG_ALL * 4);
  float* norm    = (float*)alloc(N_NODES * 4);
  float* asn     = (float*)alloc(N_NODES * 2 * 4);
  float* adn     = (float*)alloc(N_NODES * 2 * 4);
  float* stats   = (float*)alloc(1024 * 4);
  int*   bsum    = (int*)alloc(128 * 4);
  int*   boff    = (int*)alloc(128 * 4);
  int*   start   = (int*)alloc((NB + 1) * 4);
  float* p       = (float*)alloc(NB * 1024 * 4);
  float* z1      = (float*)alloc(NB * HID * 4);
  float* z2      = (float*)alloc(NB * 256 * 4);
  // x hi/lo alias buf0 (dead before buf0 first written by gcn_agg)
  unsigned short* xhi = (unsigned short*)buf0;
  unsigned short* xlo = xhi + (size_t)N_NODES * F_IN;
  f16* hbuf = (f16*)buf1;   // fp16 GEMM output view (layers 2-5)

  const dim3 blk256(256);
  const dim3 mmGrid(4, M_PAD / 128);
  const int statGrid = (N_NODES + 127) / 128;

  // --- graph preprocessing ---
  hipMemsetAsync(deg, 0, N_NODES * 4, stream);
  deg_count<<<(EDG_ALL + 255) / 256, blk256, 0, stream>>>(ei, deg);
  scan_p1<<<NBLK_SCAN, blk256, 0, stream>>>(deg, bsum);
  scan_p2<<<1, 128, 0, stream>>>(bsum, boff);
  scan_p3<<<NBLK_SCAN, blk256, 0, stream>>>(deg, boff, row_ptr);
  compute_norm<<<(N_NODES + 255) / 256, blk256, 0, stream>>>(deg, norm);
  hipMemcpyAsync(cursor, row_ptr, N_NODES * 4, hipMemcpyDeviceToDevice, stream);
  fill_csr<<<(EDG_ALL + 255) / 256, blk256, 0, stream>>>(ei, cursor, csr_src);

  // --- weight prep (split bf16, transposed) ---
  wtrans_split<<<dim3(HID / 32, F_IN / 32), blk256, 0, stream>>>(ft_W, wh_ft, wl_ft, F_IN, HID);
  wtrans_split<<<dim3(HID / 32, HID / 32), blk256, 0, stream>>>(gcn1_W, wh_g1, wl_g1, HID, HID);
  wtrans_split<<<dim3(HID / 32, HID / 32), blk256, 0, stream>>>(gcn2_W, wh_g2, wl_g2, HID, HID);
  wtrans_split<<<dim3(HID / 32, HID / 32), blk256, 0, stream>>>(gat1_W, wh_a1, wl_a1, HID, HID);
  wtrans_split<<<dim3(HID / 32, HID / 32), blk256, 0, stream>>>(gat2_W, wh_a2, wl_a2, HID, HID);
  ftrans<<<dim3(512 / 32, 1024 / 32), blk256, 0, stream>>>(fc1_W, fc1t, 1024, 512);
  ftrans<<<dim3(256 / 32, 512 / 32), blk256, 0, stream>>>(fc2_W, fc2t, 512, 256);
  ftrans<<<dim3((NCLS + 31) / 32, 256 / 32), blk256, 0, stream>>>(out_W, outt, 256, NCLS);

  // --- feature transform: Linear(split MFMA, fp32 out) -> BN -> LeakyReLU ---
  conv_split4<<<(N_NODES * F_IN / 4 + 255) / 256, blk256, 0, stream>>>(x, xhi, xlo, N_NODES * F_IN / 4);
  mm_split<F_IN, float><<<mmGrid, blk256, 0, stream>>>(xhi, xlo, wh_ft, wl_ft, ft_b, buf1);
  hipMemsetAsync(stats, 0, 1024 * 4, stream);
  colstats<<<statGrid, blk256, 0, stream>>>(buf1, N_NODES, stats);
  bn_act<<<statGrid, blk256, 0, stream>>>(buf1, N_NODES, stats, ft_g, ft_be, 1, ahi, alo, 0);

  // --- GCN1 ---
  mm_split<HID, f16><<<mmGrid, blk256, 0, stream>>>(ahi, alo, wh_g1, wl_g1, nullptr, hbuf);
  gcn_agg_h<<<N_NODES, blk256, 0, stream>>>(hbuf, row_ptr, csr_src, norm, gcn1_b, buf0);
  hipMemsetAsync(stats, 0, 1024 * 4, stream);
  colstats<<<statGrid, blk256, 0, stream>>>(buf0, N_NODES, stats);
  bn_act<<<statGrid, blk256, 0, stream>>>(buf0, N_NODES, stats, gbn1_g, gbn1_b, 2, ahi, alo, 0);

  // --- GCN2 ---
  mm_split<HID, f16><<<mmGrid, blk256, 0, stream>>>(ahi, alo, wh_g2, wl_g2, nullptr, hbuf);
  gcn_agg_h<<<N_NODES, blk256, 0, stream>>>(hbuf, row_ptr, csr_src, norm, gcn2_b, buf0);
  hipMemsetAsync(stats, 0, 1024 * 4, stream);
  colstats<<<statGrid, blk256, 0, stream>>>(buf0, N_NODES, stats);
  bn_act<<<statGrid, blk256, 0, stream>>>(buf0, N_NODES, stats, gbn2_g, gbn2_b, 2, ahi, alo, 0);

  // --- GAT1 ---
  mm_split<HID, f16><<<mmGrid, blk256, 0, stream>>>(ahi, alo, wh_a1, wl_a1, nullptr, hbuf);
  gat_prep_h<<<N_NODES, blk256, 0, stream>>>(hbuf, gat1_as, gat1_ad, asn, adn);
  gat_agg_h<<<N_NODES, blk256, 0, stream>>>(hbuf, row_ptr, csr_src, asn, adn, gat1_b, buf0);
  hipMemsetAsync(stats, 0, 1024 * 4, stream);
  colstats<<<statGrid, blk256, 0, stream>>>(buf0, N_NODES, stats);
  bn_act<<<statGrid, blk256, 0, stream>>>(buf0, N_NODES, stats, abn1_g, abn1_b, 2, ahi, alo, 0);

  // --- GAT2 ---
  mm_split<HID, f16><<<mmGrid, blk256, 0, stream>>>(ahi, alo, wh_a2, wl_a2, nullptr, hbuf);
  gat_prep_h<<<N_NODES, blk256, 0, stream>>>(hbuf, gat2_as, gat2_ad, asn, adn);
  gat_agg_h<<<N_NODES, blk256, 0, stream>>>(hbuf, row_ptr, csr_src, asn, adn, gat2_b, buf0);
  hipMemsetAsync(stats, 0, 1024 * 4, stream);
  colstats<<<statGrid, blk256, 0, stream>>>(buf0, N_NODES, stats);
  bn_act<<<statGrid, blk256, 0, stream>>>(buf0, N_NODES, stats, abn2_g, abn2_b, 2, ahi, alo, 1);

  // --- pooling ---
  graph_starts<<<(N_NODES + 255) / 256, blk256, 0, stream>>>(batch, start);
  pool2<<<NB, dim3(512), 0, stream>>>(buf0, start, p);

  // --- classifier ---
  fc_wave<<<dim3(NB, 128), blk256, 0, stream>>>(p, fc1t, fc1_b, z1, 1024, 512);
  bn_small<<<2, blk256, 0, stream>>>(z1, NB, 512, cbn1_g, cbn1_b, 0);
  fc_wave<<<dim3(NB, 64), blk256, 0, stream>>>(z1, fc2t, fc2_b, z2, 512, 256);
  bn_small<<<1, blk256, 0, stream>>>(z2, NB, 256, cbn2_g, cbn2_b, 1);
  fc_wave<<<dim3(NB, 10), blk256, 0, stream>>>(z2, outt, out_b, (float*)d_out, 256, NCLS);

  (void)in_sizes; (void)n_in; (void)out_size; (void)ws_size;
}

// Round 8
// 929.966 us; speedup vs baseline: 1.2523x; 1.2523x over previous
//
#include <hip/hip_runtime.h>

#define N_NODES 20000
#define N_EDGES 320000
#define EDG_ALL (N_EDGES + N_NODES)
#define F_IN 128
#define HID 512
#define NB 64
#define NCLS 38
#define M_PAD 20096        // 157 * 128
#define NBLK_SCAN ((N_NODES + 255) / 256)   // 79
#define BN_ROWS 16
#define BN_GRID ((N_NODES + BN_ROWS - 1) / BN_ROWS)   // 1250
#define POOL_SPLIT 4

typedef short bf16x8 __attribute__((ext_vector_type(8)));
typedef float f32x4 __attribute__((ext_vector_type(4)));
typedef _Float16 f16;
typedef _Float16 f16x2 __attribute__((ext_vector_type(2)));

__device__ inline unsigned short f2bf(float f) {
  union { float f; unsigned u; } v; v.f = f;
  unsigned r = v.u + 0x7FFF + ((v.u >> 16) & 1);
  return (unsigned short)(r >> 16);
}

// split f into hi(bf16) + lo(bf16 of residual)
__device__ inline void split2(float f, unsigned short& h, unsigned short& l) {
  unsigned short hh = f2bf(f);
  union { unsigned u; float f; } vh; vh.u = ((unsigned)hh) << 16;
  h = hh;
  l = f2bf(f - vh.f);
}

__device__ inline void gload16(const void* g, void* l) {
  __builtin_amdgcn_global_load_lds(
      (const __attribute__((address_space(1))) unsigned int*)g,
      (__attribute__((address_space(3))) unsigned int*)l, 16, 0, 0);
}

// ---------------- graph preprocessing ----------------

__global__ void deg_count(const int* __restrict__ ei, int* __restrict__ deg) {
  int e = blockIdx.x * blockDim.x + threadIdx.x;
  if (e >= EDG_ALL) return;
  int d = (e < N_EDGES) ? ei[N_EDGES + e] : (e - N_EDGES);
  atomicAdd(&deg[d], 1);
}

__global__ void scan_p1(const int* __restrict__ deg, int* __restrict__ bsum) {
  __shared__ int sh[256];
  int b = blockIdx.x, t = threadIdx.x, i = b * 256 + t;
  sh[t] = (i < N_NODES) ? deg[i] : 0;
  __syncthreads();
  for (int o = 128; o > 0; o >>= 1) {
    if (t < o) sh[t] += sh[t + o];
    __syncthreads();
  }
  if (t == 0) bsum[b] = sh[0];
}

__global__ void scan_p2(const int* __restrict__ bsum, int* __restrict__ boff) {
  __shared__ int sh[128];
  int t = threadIdx.x;
  sh[t] = (t < NBLK_SCAN) ? bsum[t] : 0;
  __syncthreads();
  for (int o = 1; o < 128; o <<= 1) {
    int v = (t >= o) ? sh[t - o] : 0;
    __syncthreads();
    sh[t] += v;
    __syncthreads();
  }
  boff[t] = (t == 0) ? 0 : sh[t - 1];
}

__global__ void scan_p3(const int* __restrict__ deg, const int* __restrict__ boff,
                        int* __restrict__ row_ptr) {
  __shared__ int sh[256];
  int b = blockIdx.x, t = threadIdx.x, i = b * 256 + t;
  sh[t] = (i < N_NODES) ? deg[i] : 0;
  __syncthreads();
  for (int o = 1; o < 256; o <<= 1) {
    int v = (t >= o) ? sh[t - o] : 0;
    __syncthreads();
    sh[t] += v;
    __syncthreads();
  }
  if (i < N_NODES) row_ptr[i + 1] = boff[b] + sh[t];
  if (i == 0) row_ptr[0] = 0;
}

__global__ void compute_norm(const int* __restrict__ deg, float* __restrict__ norm) {
  int i = blockIdx.x * blockDim.x + threadIdx.x;
  if (i >= N_NODES) return;
  norm[i] = rsqrtf(fmaxf((float)deg[i], 1.f));
}

__global__ void fill_csr(const int* __restrict__ ei, int* __restrict__ cursor,
                         int* __restrict__ csr_src) {
  int e = blockIdx.x * blockDim.x + threadIdx.x;
  if (e >= EDG_ALL) return;
  int s, d;
  if (e < N_EDGES) { s = ei[e]; d = ei[N_EDGES + e]; }
  else { s = d = e - N_EDGES; }
  int pos = atomicAdd(&cursor[d], 1);
  csr_src[pos] = s;
}

// ---------------- conversions / transposes ----------------

__global__ void conv_split4(const float* __restrict__ in, unsigned short* __restrict__ hi,
                            unsigned short* __restrict__ lo, int n4) {
  int i = blockIdx.x * blockDim.x + threadIdx.x;
  if (i >= n4) return;
  float4 v = ((const float4*)in)[i];
  ushort4 h, l;
  split2(v.x, h.x, l.x); split2(v.y, h.y, l.y);
  split2(v.z, h.z, l.z); split2(v.w, h.w, l.w);
  ((ushort4*)hi)[i] = h;
  ((ushort4*)lo)[i] = l;
}

// W [K][N] fp32 -> WT hi/lo [N][K] bf16   (K, N multiples of 32)
__global__ __launch_bounds__(256) void wtrans_split(const float* __restrict__ W,
                                                    unsigned short* __restrict__ WTh,
                                                    unsigned short* __restrict__ WTl,
                                                    int K, int N) {
  __shared__ float sh[32][33];
  int k0 = blockIdx.y * 32, n0 = blockIdx.x * 32;
  int r = threadIdx.x >> 5, c = threadIdx.x & 31;
#pragma unroll
  for (int i = 0; i < 4; ++i)
    sh[r + 8 * i][c] = W[(size_t)(k0 + r + 8 * i) * N + n0 + c];
  __syncthreads();
#pragma unroll
  for (int i = 0; i < 4; ++i) {
    unsigned short h, l;
    split2(sh[c][r + 8 * i], h, l);
    WTh[(size_t)(n0 + r + 8 * i) * K + k0 + c] = h;
    WTl[(size_t)(n0 + r + 8 * i) * K + k0 + c] = l;
  }
}

// W [K][N] fp32 -> WT [N][K] fp32, bounds-checked
__global__ __launch_bounds__(256) void ftrans(const float* __restrict__ W,
                                              float* __restrict__ WT, int K, int N) {
  __shared__ float sh[32][33];
  int k0 = blockIdx.y * 32, n0 = blockIdx.x * 32;
  int r = threadIdx.x >> 5, c = threadIdx.x & 31;
#pragma unroll
  for (int i = 0; i < 4; ++i) {
    int k = k0 + r + 8 * i, n = n0 + c;
    sh[r + 8 * i][c] = (k < K && n < N) ? W[(size_t)k * N + n] : 0.f;
  }
  __syncthreads();
#pragma unroll
  for (int i = 0; i < 4; ++i) {
    int n = n0 + r + 8 * i, k = k0 + c;
    if (n < N && k < K) WT[(size_t)n * K + k] = sh[c][r + 8 * i];
  }
}

// ---------------- split-bf16 MFMA GEMM ----------------
// C[M_PAD][512] = (Ah+Al)[M_PAD][K] * (Bh+Bl)[512][K]^T, dropping Al*Bl

template <int K, typename OT>
__global__ __launch_bounds__(256) void mm_split(const unsigned short* __restrict__ Ah,
                                                const unsigned short* __restrict__ Al,
                                                const unsigned short* __restrict__ Bh,
                                                const unsigned short* __restrict__ Bl,
                                                const float* __restrict__ bias,
                                                OT* __restrict__ C) {
  __shared__ unsigned short AsH[4096], AsL[4096], BsH[4096], BsL[4096];
  const int t = threadIdx.x;
  const int wid = t >> 6, l = t & 63;
  const int row0 = blockIdx.y * 128;
  const int col0 = blockIdx.x * 128;
  const int wm = wid >> 1, wn = wid & 1;

  f32x4 acc[4][4];
#pragma unroll
  for (int m = 0; m < 4; ++m)
#pragma unroll
    for (int n = 0; n < 4; ++n)
#pragma unroll
      for (int q = 0; q < 4; ++q) acc[m][n][q] = 0.f;

  const size_t aoff = (size_t)(row0 + wid * 32 + (l >> 2)) * K + (l & 3) * 8;
  const size_t boff = (size_t)(col0 + wid * 32 + (l >> 2)) * K + (l & 3) * 8;
  const unsigned short* gAh0 = Ah + aoff; const unsigned short* gAh1 = gAh0 + (size_t)16 * K;
  const unsigned short* gAl0 = Al + aoff; const unsigned short* gAl1 = gAl0 + (size_t)16 * K;
  const unsigned short* gBh0 = Bh + boff; const unsigned short* gBh1 = gBh0 + (size_t)16 * K;
  const unsigned short* gBl0 = Bl + boff; const unsigned short* gBl1 = gBl0 + (size_t)16 * K;
  unsigned short* lAh0 = &AsH[(wid * 2 + 0) * 512];
  unsigned short* lAh1 = &AsH[(wid * 2 + 1) * 512];
  unsigned short* lAl0 = &AsL[(wid * 2 + 0) * 512];
  unsigned short* lAl1 = &AsL[(wid * 2 + 1) * 512];
  unsigned short* lBh0 = &BsH[(wid * 2 + 0) * 512];
  unsigned short* lBh1 = &BsH[(wid * 2 + 1) * 512];
  unsigned short* lBl0 = &BsL[(wid * 2 + 0) * 512];
  unsigned short* lBl1 = &BsL[(wid * 2 + 1) * 512];

  const int lr = l & 15, kq = (l >> 4) * 8;

  for (int kt = 0; kt < K / 32; ++kt) {
    const int ko = kt * 32;
    gload16(gAh0 + ko, lAh0);
    gload16(gAh1 + ko, lAh1);
    gload16(gAl0 + ko, lAl0);
    gload16(gAl1 + ko, lAl1);
    gload16(gBh0 + ko, lBh0);
    gload16(gBh1 + ko, lBh1);
    gload16(gBl0 + ko, lBl0);
    gload16(gBl1 + ko, lBl1);
    __syncthreads();
    bf16x8 ah[4], al[4], bh[4], bl[4];
#pragma unroll
    for (int m = 0; m < 4; ++m) {
      int ro = (wm * 64 + m * 16 + lr) * 32 + kq;
      ah[m] = *(const bf16x8*)&AsH[ro];
      al[m] = *(const bf16x8*)&AsL[ro];
    }
#pragma unroll
    for (int n = 0; n < 4; ++n) {
      int ro = (wn * 64 + n * 16 + lr) * 32 + kq;
      bh[n] = *(const bf16x8*)&BsH[ro];
      bl[n] = *(const bf16x8*)&BsL[ro];
    }
#pragma unroll
    for (int m = 0; m < 4; ++m)
#pragma unroll
      for (int n = 0; n < 4; ++n) {
        acc[m][n] = __builtin_amdgcn_mfma_f32_16x16x32_bf16(ah[m], bh[n], acc[m][n], 0, 0, 0);
        acc[m][n] = __builtin_amdgcn_mfma_f32_16x16x32_bf16(al[m], bh[n], acc[m][n], 0, 0, 0);
        acc[m][n] = __builtin_amdgcn_mfma_f32_16x16x32_bf16(ah[m], bl[n], acc[m][n], 0, 0, 0);
      }
    __syncthreads();
  }

  const int lg = l >> 4;
#pragma unroll
  for (int m = 0; m < 4; ++m) {
    int row = row0 + wm * 64 + m * 16 + lg * 4;
#pragma unroll
    for (int n = 0; n < 4; ++n) {
      int col = col0 + wn * 64 + n * 16 + lr;
      float bv = bias ? bias[col] : 0.f;
#pragma unroll
      for (int j = 0; j < 4; ++j)
        C[(size_t)(row + j) * HID + col] = (OT)(acc[m][n][j] + bv);
    }
  }
}

// ---------------- batchnorm (train-mode, over rows) ----------------

__global__ __launch_bounds__(256) void colstats(const float* __restrict__ X, int n,
                                                float* __restrict__ stats) {
  int t = threadIdx.x;
  int r0 = blockIdx.x * BN_ROWS;
  int r1 = min(r0 + BN_ROWS, n);
  float s0 = 0, q0 = 0, s1 = 0, q1 = 0;
  for (int r = r0; r < r1; ++r) {
    float a = X[(size_t)r * HID + t];
    float b = X[(size_t)r * HID + t + 256];
    s0 += a; q0 += a * a;
    s1 += b; q1 += b * b;
  }
  atomicAdd(&stats[t], s0);
  atomicAdd(&stats[t + 256], s1);
  atomicAdd(&stats[HID + t], q0);
  atomicAdd(&stats[HID + t + 256], q1);
}

// act: 1=leaky_relu(0.2), 2=elu ; writes bf16 hi/lo planes; fp32 X in place only if writeX
__global__ __launch_bounds__(256) void bn_act(float* __restrict__ X, int n,
                                              const float* __restrict__ stats,
                                              const float* __restrict__ g,
                                              const float* __restrict__ b, int act,
                                              unsigned short* __restrict__ hio,
                                              unsigned short* __restrict__ loo,
                                              int writeX) {
  int t = threadIdx.x;
  int r0 = blockIdx.x * BN_ROWS;
  int r1 = min(r0 + BN_ROWS, n);
  float invn = 1.f / (float)n;
  float mu0 = stats[t] * invn, mu1 = stats[t + 256] * invn;
  float v0 = stats[HID + t] * invn - mu0 * mu0;
  float v1 = stats[HID + t + 256] * invn - mu1 * mu1;
  float sc0 = g[t] * rsqrtf(v0 + 1e-5f);
  float sc1 = g[t + 256] * rsqrtf(v1 + 1e-5f);
  float b0 = b[t], b1 = b[t + 256];
  for (int r = r0; r < r1; ++r) {
    float y0 = sc0 * (X[(size_t)r * HID + t] - mu0) + b0;
    float y1 = sc1 * (X[(size_t)r * HID + t + 256] - mu1) + b1;
    if (act == 1) {
      y0 = y0 > 0.f ? y0 : 0.2f * y0;
      y1 = y1 > 0.f ? y1 : 0.2f * y1;
    } else {
      y0 = y0 > 0.f ? y0 : expm1f(y0);
      y1 = y1 > 0.f ? y1 : expm1f(y1);
    }
    unsigned short h0, l0, h1, l1;
    split2(y0, h0, l0);
    split2(y1, h1, l1);
    hio[(size_t)r * HID + t] = h0;
    hio[(size_t)r * HID + t + 256] = h1;
    loo[(size_t)r * HID + t] = l0;
    loo[(size_t)r * HID + t + 256] = l1;
    if (writeX) {
      X[(size_t)r * HID + t] = y0;
      X[(size_t)r * HID + t + 256] = y1;
    }
  }
}

// ---------------- GCN aggregation (fp16 features, unrolled x8) ----------------

__global__ __launch_bounds__(256) void gcn_agg_h(
    const f16* __restrict__ h, const int* __restrict__ row_ptr,
    const int* __restrict__ csr_src, const float* __restrict__ norm,
    const float* __restrict__ bias, float* __restrict__ out) {
  int i = blockIdx.x;
  int t = threadIdx.x;
  int beg = row_ptr[i], end = row_ptr[i + 1];
  float ni = norm[i];
  const f16x2* h2 = (const f16x2*)h;
  float a0 = 0.f, a1 = 0.f;
  int e = beg;
  for (; e + 8 <= end; e += 8) {
    int s[8]; float c[8]; f16x2 v[8];
#pragma unroll
    for (int k = 0; k < 8; ++k) s[k] = csr_src[e + k];
#pragma unroll
    for (int k = 0; k < 8; ++k) c[k] = norm[s[k]] * ni;
#pragma unroll
    for (int k = 0; k < 8; ++k) v[k] = h2[(size_t)s[k] * 256 + t];
#pragma unroll
    for (int k = 0; k < 8; ++k) {
      a0 += c[k] * (float)v[k].x;
      a1 += c[k] * (float)v[k].y;
    }
  }
  for (; e < end; ++e) {
    int s = csr_src[e];
    float c = norm[s] * ni;
    f16x2 hv = h2[(size_t)s * 256 + t];
    a0 += c * (float)hv.x;
    a1 += c * (float)hv.y;
  }
  float2 bv = ((const float2*)bias)[t];
  float2 o; o.x = a0 + bv.x; o.y = a1 + bv.y;
  ((float2*)out)[(size_t)i * 256 + t] = o;
}

// ---------------- GAT ----------------

__device__ inline float wave_sum(float v) {
#pragma unroll
  for (int o = 32; o > 0; o >>= 1) v += __shfl_down(v, o);
  return v;
}
__device__ inline float wave_max(float v) {
#pragma unroll
  for (int o = 32; o > 0; o >>= 1) v = fmaxf(v, __shfl_down(v, o));
  return v;
}

// asn/adn from fp16 h: thread t covers features 2t,2t+1 (head = t>=128)
__global__ __launch_bounds__(256) void gat_prep_h(
    const f16* __restrict__ h, const float* __restrict__ a_src,
    const float* __restrict__ a_dst, float* __restrict__ asn, float* __restrict__ adn) {
  int i = blockIdx.x;
  int t = threadIdx.x;
  f16x2 hv = ((const f16x2*)h)[(size_t)i * 256 + t];
  float2 as2 = ((const float2*)a_src)[t];
  float2 ad2 = ((const float2*)a_dst)[t];
  float h0 = (float)hv.x, h1 = (float)hv.y;
  float s = h0 * as2.x + h1 * as2.y;
  float d = h0 * ad2.x + h1 * ad2.y;
  s = wave_sum(s); d = wave_sum(d);
  __shared__ float red[4][2];
  int w = t >> 6;
  if ((t & 63) == 0) { red[w][0] = s; red[w][1] = d; }
  __syncthreads();
  if (t == 0) {
    asn[2 * i]     = red[0][0] + red[1][0];   // head 0 = waves 0,1 (threads 0-127)
    asn[2 * i + 1] = red[2][0] + red[3][0];   // head 1 = waves 2,3
    adn[2 * i]     = red[0][1] + red[1][1];
    adn[2 * i + 1] = red[2][1] + red[3][1];
  }
}

// 2-pass: per-node max, then fused sumexp + weighted fp16 gather (divide at end)
__global__ __launch_bounds__(256) void gat_agg_h(
    const f16* __restrict__ h, const int* __restrict__ row_ptr,
    const int* __restrict__ csr_src, const float* __restrict__ asn,
    const float* __restrict__ adn, const float* __restrict__ bias,
    float* __restrict__ out) {
  int i = blockIdx.x;
  int t = threadIdx.x;
  int beg = row_ptr[i], end = row_ptr[i + 1];
  float ad0 = adn[2 * i], ad1 = adn[2 * i + 1];

  // pass 1: max of leaky_relu(as[src]+ad[dst]) per head
  float m0 = -3.4e38f, m1 = -3.4e38f;
#pragma unroll 4
  for (int e = beg + t; e < end; e += 256) {
    int s = csr_src[e];
    float e0 = asn[2 * s] + ad0;     e0 = e0 > 0.f ? e0 : 0.2f * e0;
    float e1 = asn[2 * s + 1] + ad1; e1 = e1 > 0.f ? e1 : 0.2f * e1;
    m0 = fmaxf(m0, e0); m1 = fmaxf(m1, e1);
  }
  __shared__ float red0[4], red1[4];
  float r0 = wave_max(m0), r1 = wave_max(m1);
  if ((t & 63) == 0) { red0[t >> 6] = r0; red1[t >> 6] = r1; }
  __syncthreads();
  float M0 = fmaxf(fmaxf(red0[0], red0[1]), fmaxf(red0[2], red0[3]));
  float M1 = fmaxf(fmaxf(red1[0], red1[1]), fmaxf(red1[2], red1[3]));
  __syncthreads();

  // pass 2: fused — chunk weights (unnormalized) + feature gather + weight sums
  __shared__ float w0s[64], w1s[64];
  __shared__ int ss[64];
  __shared__ float sS0, sS1;
  const f16x2* h2 = (const f16x2*)h;
  float acc0 = 0.f, acc1 = 0.f;
  float sw0 = 0.f, sw1 = 0.f;   // partial weight sums (threads 0-63 only)
  for (int c = beg; c < end; c += 64) {
    int nc = min(64, end - c);
    if (t < nc) {
      int s = csr_src[c + t];
      ss[t] = s;
      float e0 = asn[2 * s] + ad0;     e0 = e0 > 0.f ? e0 : 0.2f * e0;
      float e1 = asn[2 * s + 1] + ad1; e1 = e1 > 0.f ? e1 : 0.2f * e1;
      float w0 = expf(e0 - M0), w1 = expf(e1 - M1);
      w0s[t] = w0; w1s[t] = w1;
      sw0 += w0; sw1 += w1;
    }
    __syncthreads();
    int j = 0;
    for (; j + 8 <= nc; j += 8) {
      int s[8]; f16x2 v[8]; float u[8];
#pragma unroll
      for (int k = 0; k < 8; ++k) s[k] = ss[j + k];
#pragma unroll
      for (int k = 0; k < 8; ++k) v[k] = h2[(size_t)s[k] * 256 + t];
#pragma unroll
      for (int k = 0; k < 8; ++k) u[k] = (t < 128) ? w0s[j + k] : w1s[j + k];
#pragma unroll
      for (int k = 0; k < 8; ++k) {
        acc0 += u[k] * (float)v[k].x;
        acc1 += u[k] * (float)v[k].y;
      }
    }
    for (; j < nc; ++j) {
      int s = ss[j];
      f16x2 hv = h2[(size_t)s * 256 + t];
      float w = (t < 128) ? w0s[j] : w1s[j];
      acc0 += w * (float)hv.x;
      acc1 += w * (float)hv.y;
    }
    __syncthreads();
  }
  // reduce weight sums over wave 0 (threads 0-63 hold partials)
  if (t < 64) {
    float a = wave_sum(sw0);
    float b = wave_sum(sw1);
    if (t == 0) { sS0 = a; sS1 = b; }
  }
  __syncthreads();
  float iS = (t < 128) ? (1.f / sS0) : (1.f / sS1);
  float2 bv = ((const float2*)bias)[t];
  float2 o; o.x = acc0 * iS + bv.x; o.y = acc1 * iS + bv.y;
  ((float2*)out)[(size_t)i * 256 + t] = o;
}

// ---------------- pooling ----------------

__global__ void graph_starts(const int* __restrict__ batch, int* __restrict__ start) {
  int i = blockIdx.x * blockDim.x + threadIdx.x;
  if (i >= N_NODES) return;
  int b = batch[i];
  int bp = (i == 0) ? -1 : batch[i - 1];
  for (int g = bp + 1; g <= b; ++g) start[g] = i;
  if (i == N_NODES - 1) {
    for (int g = b + 1; g <= NB; ++g) start[g] = N_NODES;
  }
}

// partial pool: grid (NB, POOL_SPLIT); writes pp_sum/pp_max [b][chunk][512]
__global__ __launch_bounds__(512) void pool_part(const float* __restrict__ h,
                                                 const int* __restrict__ start,
                                                 float* __restrict__ pp_sum,
                                                 float* __restrict__ pp_max) {
  int b = blockIdx.x, ch = blockIdx.y, t = threadIdx.x;
  int s = start[b], e = start[b + 1];
  int len = e - s;
  int c0 = s + (len * ch) / POOL_SPLIT;
  int c1 = s + (len * (ch + 1)) / POOL_SPLIT;
  float sum = 0.f, mx = -3.4e38f;
  int r = c0;
  for (; r + 4 <= c1; r += 4) {
    float v0 = h[(size_t)(r + 0) * HID + t];
    float v1 = h[(size_t)(r + 1) * HID + t];
    float v2 = h[(size_t)(r + 2) * HID + t];
    float v3 = h[(size_t)(r + 3) * HID + t];
    sum += v0 + v1 + v2 + v3;
    mx = fmaxf(mx, fmaxf(fmaxf(v0, v1), fmaxf(v2, v3)));
  }
  for (; r < c1; ++r) {
    float v = h[(size_t)r * HID + t];
    sum += v; mx = fmaxf(mx, v);
  }
  pp_sum[((size_t)b * POOL_SPLIT + ch) * HID + t] = sum;
  pp_max[((size_t)b * POOL_SPLIT + ch) * HID + t] = mx;
}

__global__ __launch_bounds__(512) void pool_comb(const float* __restrict__ pp_sum,
                                                 const float* __restrict__ pp_max,
                                                 const int* __restrict__ start,
                                                 float* __restrict__ p) {
  int b = blockIdx.x, t = threadIdx.x;
  float sum = 0.f, mx = -3.4e38f;
#pragma unroll
  for (int ch = 0; ch < POOL_SPLIT; ++ch) {
    sum += pp_sum[((size_t)b * POOL_SPLIT + ch) * HID + t];
    mx = fmaxf(mx, pp_max[((size_t)b * POOL_SPLIT + ch) * HID + t]);
  }
  float cnt = (float)(start[b + 1] - start[b]);
  p[b * 1024 + t] = sum / fmaxf(cnt, 1.f);
  p[b * 1024 + 512 + t] = mx;
}

// ---------------- classifier ----------------

__global__ __launch_bounds__(256) void fc_wave(const float* __restrict__ A,
                                               const float* __restrict__ WT,
                                               const float* __restrict__ bias,
                                               float* __restrict__ C, int K, int Ncol) {
  int r = blockIdx.x;
  int wid = threadIdx.x >> 6, l = threadIdx.x & 63;
  int c = blockIdx.y * 4 + wid;
  if (c >= Ncol) return;
  const float* a = A + (size_t)r * K;
  const float* w = WT + (size_t)c * K;
  float s = 0.f;
  for (int k = l; k < K; k += 64) s += a[k] * w[k];
#pragma unroll
  for (int o = 32; o > 0; o >>= 1) s += __shfl_down(s, o);
  if (l == 0) C[(size_t)r * Ncol + c] = s + bias[c];
}

__global__ void bn_small(float* __restrict__ X, int R, int C,
                         const float* __restrict__ g, const float* __restrict__ b, int act) {
  int c = blockIdx.x * blockDim.x + threadIdx.x;
  if (c >= C) return;
  float s = 0.f, q = 0.f;
  for (int r = 0; r < R; ++r) {
    float v = X[r * C + c];
    s += v; q += v * v;
  }
  float mu = s / R;
  float var = q / R - mu * mu;
  float sc = g[c] * rsqrtf(var + 1e-5f);
  float bb = b[c];
  for (int r = 0; r < R; ++r) {
    float v = sc * (X[r * C + c] - mu) + bb;
    if (act == 1) v = v > 0.f ? v : 0.2f * v;
    X[r * C + c] = v;
  }
}

// ---------------- launch ----------------

extern "C" void kernel_launch(void* const* d_in, const int* in_sizes, int n_in,
                              void* d_out, int out_size, void* d_ws, size_t ws_size,
                              hipStream_t stream) {
  const float* x      = (const float*)d_in[0];
  const int*   ei     = (const int*)d_in[1];
  const int*   batch  = (const int*)d_in[2];
  const float* ft_W   = (const float*)d_in[3];
  const float* ft_b   = (const float*)d_in[4];
  const float* ft_g   = (const float*)d_in[5];
  const float* ft_be  = (const float*)d_in[6];
  const float* gcn1_W = (const float*)d_in[7];
  const float* gcn1_b = (const float*)d_in[8];
  const float* gbn1_g = (const float*)d_in[9];
  const float* gbn1_b = (const float*)d_in[10];
  const float* gcn2_W = (const float*)d_in[11];
  const float* gcn2_b = (const float*)d_in[12];
  const float* gbn2_g = (const float*)d_in[13];
  const float* gbn2_b = (const float*)d_in[14];
  const float* gat1_W = (const float*)d_in[15];
  const float* gat1_as= (const float*)d_in[16];
  const float* gat1_ad= (const float*)d_in[17];
  const float* gat1_b = (const float*)d_in[18];
  const float* abn1_g = (const float*)d_in[19];
  const float* abn1_b = (const float*)d_in[20];
  const float* gat2_W = (const float*)d_in[21];
  const float* gat2_as= (const float*)d_in[22];
  const float* gat2_ad= (const float*)d_in[23];
  const float* gat2_b = (const float*)d_in[24];
  const float* abn2_g = (const float*)d_in[25];
  const float* abn2_b = (const float*)d_in[26];
  const float* fc1_W  = (const float*)d_in[27];
  const float* fc1_b  = (const float*)d_in[28];
  const float* cbn1_g = (const float*)d_in[29];
  const float* cbn1_b = (const float*)d_in[30];
  const float* fc2_W  = (const float*)d_in[31];
  const float* fc2_b  = (const float*)d_in[32];
  const float* cbn2_g = (const float*)d_in[33];
  const float* cbn2_b = (const float*)d_in[34];
  const float* out_W  = (const float*)d_in[35];
  const float* out_b  = (const float*)d_in[36];

  char* ws = (char*)d_ws;
  size_t off = 0;
  auto alloc = [&](size_t bytes) -> void* {
    void* p = ws + off;
    off = (off + bytes + 255) & ~(size_t)255;
    return p;
  };

  float* buf0 = (float*)alloc((size_t)N_NODES * HID * 4);      // fp32 agg out (aliases xhi/xlo early)
  float* buf1 = (float*)alloc((size_t)M_PAD * HID * 4);        // GEMM out (fp32 for ft; fp16 view for layers)
  unsigned short* ahi = (unsigned short*)alloc((size_t)N_NODES * HID * 2);
  unsigned short* alo = (unsigned short*)alloc((size_t)N_NODES * HID * 2);
  unsigned short* wh_ft = (unsigned short*)alloc((size_t)HID * F_IN * 2);
  unsigned short* wl_ft = (unsigned short*)alloc((size_t)HID * F_IN * 2);
  unsigned short* wh_g1 = (unsigned short*)alloc((size_t)HID * HID * 2);
  unsigned short* wl_g1 = (unsigned short*)alloc((size_t)HID * HID * 2);
  unsigned short* wh_g2 = (unsigned short*)alloc((size_t)HID * HID * 2);
  unsigned short* wl_g2 = (unsigned short*)alloc((size_t)HID * HID * 2);
  unsigned short* wh_a1 = (unsigned short*)alloc((size_t)HID * HID * 2);
  unsigned short* wl_a1 = (unsigned short*)alloc((size_t)HID * HID * 2);
  unsigned short* wh_a2 = (unsigned short*)alloc((size_t)HID * HID * 2);
  unsigned short* wl_a2 = (unsigned short*)alloc((size_t)HID * HID * 2);
  float* fc1t = (float*)alloc((size_t)512 * 1024 * 4);
  float* fc2t = (float*)alloc((size_t)256 * 512 * 4);
  float* outt = (float*)alloc((size_t)NCLS * 256 * 4);
  int*   row_ptr = (int*)alloc((N_NODES + 1) * 4);
  int*   cursor  = (int*)alloc(N_NODES * 4);
  int*   deg     = (int*)alloc(N_NODES * 4);
  int*   csr_src = (int*)alloc(EDG_ALL * 4);
  float* norm    = (float*)alloc(N_NODES * 4);
  float* asn     = (float*)alloc(N_NODES * 2 * 4);
  float* adn     = (float*)alloc(N_NODES * 2 * 4);
  float* stats   = (float*)alloc(1024 * 4);
  int*   bsum    = (int*)alloc(128 * 4);
  int*   boff    = (int*)alloc(128 * 4);
  int*   start   = (int*)alloc((NB + 1) * 4);
  float* p       = (float*)alloc(NB * 1024 * 4);
  float* pp_sum  = (float*)alloc((size_t)NB * POOL_SPLIT * HID * 4);
  float* pp_max  = (float*)alloc((size_t)NB * POOL_SPLIT * HID * 4);
  float* z1      = (float*)alloc(NB * HID * 4);
  float* z2      = (float*)alloc(NB * 256 * 4);
  // x hi/lo alias buf0 (dead before buf0 first written by gcn_agg)
  unsigned short* xhi = (unsigned short*)buf0;
  unsigned short* xlo = xhi + (size_t)N_NODES * F_IN;
  f16* hbuf = (f16*)buf1;   // fp16 GEMM output view (layers 2-5)

  const dim3 blk256(256);
  const dim3 mmGrid(4, M_PAD / 128);

  // --- graph preprocessing ---
  hipMemsetAsync(deg, 0, N_NODES * 4, stream);
  deg_count<<<(EDG_ALL + 255) / 256, blk256, 0, stream>>>(ei, deg);
  scan_p1<<<NBLK_SCAN, blk256, 0, stream>>>(deg, bsum);
  scan_p2<<<1, 128, 0, stream>>>(bsum, boff);
  scan_p3<<<NBLK_SCAN, blk256, 0, stream>>>(deg, boff, row_ptr);
  compute_norm<<<(N_NODES + 255) / 256, blk256, 0, stream>>>(deg, norm);
  hipMemcpyAsync(cursor, row_ptr, N_NODES * 4, hipMemcpyDeviceToDevice, stream);
  fill_csr<<<(EDG_ALL + 255) / 256, blk256, 0, stream>>>(ei, cursor, csr_src);

  // --- weight prep (split bf16, transposed) ---
  wtrans_split<<<dim3(HID / 32, F_IN / 32), blk256, 0, stream>>>(ft_W, wh_ft, wl_ft, F_IN, HID);
  wtrans_split<<<dim3(HID / 32, HID / 32), blk256, 0, stream>>>(gcn1_W, wh_g1, wl_g1, HID, HID);
  wtrans_split<<<dim3(HID / 32, HID / 32), blk256, 0, stream>>>(gcn2_W, wh_g2, wl_g2, HID, HID);
  wtrans_split<<<dim3(HID / 32, HID / 32), blk256, 0, stream>>>(gat1_W, wh_a1, wl_a1, HID, HID);
  wtrans_split<<<dim3(HID / 32, HID / 32), blk256, 0, stream>>>(gat2_W, wh_a2, wl_a2, HID, HID);
  ftrans<<<dim3(512 / 32, 1024 / 32), blk256, 0, stream>>>(fc1_W, fc1t, 1024, 512);
  ftrans<<<dim3(256 / 32, 512 / 32), blk256, 0, stream>>>(fc2_W, fc2t, 512, 256);
  ftrans<<<dim3((NCLS + 31) / 32, 256 / 32), blk256, 0, stream>>>(out_W, outt, 256, NCLS);

  // --- feature transform: Linear(split MFMA, fp32 out) -> BN -> LeakyReLU ---
  conv_split4<<<(N_NODES * F_IN / 4 + 255) / 256, blk256, 0, stream>>>(x, xhi, xlo, N_NODES * F_IN / 4);
  mm_split<F_IN, float><<<mmGrid, blk256, 0, stream>>>(xhi, xlo, wh_ft, wl_ft, ft_b, buf1);
  hipMemsetAsync(stats, 0, 1024 * 4, stream);
  colstats<<<BN_GRID, blk256, 0, stream>>>(buf1, N_NODES, stats);
  bn_act<<<BN_GRID, blk256, 0, stream>>>(buf1, N_NODES, stats, ft_g, ft_be, 1, ahi, alo, 0);

  // --- GCN1 ---
  mm_split<HID, f16><<<mmGrid, blk256, 0, stream>>>(ahi, alo, wh_g1, wl_g1, nullptr, hbuf);
  gcn_agg_h<<<N_NODES, blk256, 0, stream>>>(hbuf, row_ptr, csr_src, norm, gcn1_b, buf0);
  hipMemsetAsync(stats, 0, 1024 * 4, stream);
  colstats<<<BN_GRID, blk256, 0, stream>>>(buf0, N_NODES, stats);
  bn_act<<<BN_GRID, blk256, 0, stream>>>(buf0, N_NODES, stats, gbn1_g, gbn1_b, 2, ahi, alo, 0);

  // --- GCN2 ---
  mm_split<HID, f16><<<mmGrid, blk256, 0, stream>>>(ahi, alo, wh_g2, wl_g2, nullptr, hbuf);
  gcn_agg_h<<<N_NODES, blk256, 0, stream>>>(hbuf, row_ptr, csr_src, norm, gcn2_b, buf0);
  hipMemsetAsync(stats, 0, 1024 * 4, stream);
  colstats<<<BN_GRID, blk256, 0, stream>>>(buf0, N_NODES, stats);
  bn_act<<<BN_GRID, blk256, 0, stream>>>(buf0, N_NODES, stats, gbn2_g, gbn2_b, 2, ahi, alo, 0);

  // --- GAT1 ---
  mm_split<HID, f16><<<mmGrid, blk256, 0, stream>>>(ahi, alo, wh_a1, wl_a1, nullptr, hbuf);
  gat_prep_h<<<N_NODES, blk256, 0, stream>>>(hbuf, gat1_as, gat1_ad, asn, adn);
  gat_agg_h<<<N_NODES, blk256, 0, stream>>>(hbuf, row_ptr, csr_src, asn, adn, gat1_b, buf0);
  hipMemsetAsync(stats, 0, 1024 * 4, stream);
  colstats<<<BN_GRID, blk256, 0, stream>>>(buf0, N_NODES, stats);
  bn_act<<<BN_GRID, blk256, 0, stream>>>(buf0, N_NODES, stats, abn1_g, abn1_b, 2, ahi, alo, 0);

  // --- GAT2 ---
  mm_split<HID, f16><<<mmGrid, blk256, 0, stream>>>(ahi, alo, wh_a2, wl_a2, nullptr, hbuf);
  gat_prep_h<<<N_NODES, blk256, 0, stream>>>(hbuf, gat2_as, gat2_ad, asn, adn);
  gat_agg_h<<<N_NODES, blk256, 0, stream>>>(hbuf, row_ptr, csr_src, asn, adn, gat2_b, buf0);
  hipMemsetAsync(stats, 0, 1024 * 4, stream);
  colstats<<<BN_GRID, blk256, 0, stream>>>(buf0, N_NODES, stats);
  bn_act<<<BN_GRID, blk256, 0, stream>>>(buf0, N_NODES, stats, abn2_g, abn2_b, 2, ahi, alo, 1);

  // --- pooling ---
  graph_starts<<<(N_NODES + 255) / 256, blk256, 0, stream>>>(batch, start);
  pool_part<<<dim3(NB, POOL_SPLIT), dim3(512), 0, stream>>>(buf0, start, pp_sum, pp_max);
  pool_comb<<<NB, dim3(512), 0, stream>>>(pp_sum, pp_max, start, p);

  // --- classifier ---
  fc_wave<<<dim3(NB, 128), blk256, 0, stream>>>(p, fc1t, fc1_b, z1, 1024, 512);
  bn_small<<<2, blk256, 0, stream>>>(z1, NB, 512, cbn1_g, cbn1_b, 0);
  fc_wave<<<dim3(NB, 64), blk256, 0, stream>>>(z1, fc2t, fc2_b, z2, 512, 256);
  bn_small<<<1, blk256, 0, stream>>>(z2, NB, 256, cbn2_g, cbn2_b, 1);
  fc_wave<<<dim3(NB, 10), blk256, 0, stream>>>(z2, outt, out_b, (float*)d_out, 256, NCLS);

  (void)in_sizes; (void)n_in; (void)out_size; (void)ws_size;
}